// Round 3
// baseline (286.294 us; speedup 1.0000x reference)
//
#include <hip/hip_runtime.h>

// Problem constants
#define WF 512
#define HF 256
#define CF 64
#define NDTOT 65

static constexpr size_t CH  = (size_t)HF * WF;   // one channel plane (elements)
static constexpr size_t WH  = (size_t)HF * WF;   // one (b,d) output plane (elements)
static constexpr float  INV = 1.0f / 576.0f;     // 1/(K*K*C)

// ---------------------------------------------------------------------------
// k1: per (b, y, dhalf) — horizontally box-summed channel-dot rows.
//   r[d][x] = sum_{v=x-1..x+1} sum_c x0[b,c,y,v] * x1[b,c,y,v+d-32]
// blockIdx = (dhalf, y, b). 256 threads = 4 waves.
// Thread tile: 8 cols x 8 d (wave h==3 of dhalf==1 takes 9 d to cover d=64).
//   g = t&63: cols 8g..8g+7 (lane)    h = t>>6: d = 32*dhalf + 8h + dd
// x1 row staged in XOR-swizzled LDS (576 floats incl. +-32 shift pad);
// x0 held in registers. Window = 16 floats = 4 x ds_read_b128.
// Accumulator = 72 floats/thread -> fits architectural VGPRs (no AGPR traffic).
// ---------------------------------------------------------------------------
__global__ __launch_bounds__(256)
void corr_rows(const float* __restrict__ x0, const float* __restrict__ x1,
               float* __restrict__ ws, size_t wsBStride) {
    const int dhalf = blockIdx.x;          // 0: d 0..31, 1: d 32..64
    const int y = blockIdx.y;
    const int b = blockIdx.z;
    const int t = threadIdx.x;
    const int g = t & 63;                  // col-group (lane): cols 8g..8g+7
    const int h = t >> 6;                  // d-group (wave)
    const int dbase = dhalf << 5;
    const int nd = (h == 3) ? (8 + dhalf) : 8;   // wave-uniform

    __shared__ __align__(16) float lds1[576];    // lds1[i] = x1 col (i-32), OOB -> 0

    const float* x0row = x0 + (size_t)b * CF * CH + (size_t)y * WF;
    const float* x1row = x1 + (size_t)b * CF * CH + (size_t)y * WF;

    // Swizzled staging-write addresses (granule XOR: G -> G ^ ((G>>3)&7)).
    const int G0w = t >> 2;
    const int wa0 = (((G0w      ) ^ (((G0w      ) >> 3) & 7)) << 2) | (t & 3);
    const int G1w = (t + 256) >> 2;
    const int wa1 = (((G1w      ) ^ (((G1w      ) >> 3) & 7)) << 2) | (t & 3);
    const int G2w = (t + 512) >> 2;
    const int wa2 = (((G2w      ) ^ (((G2w      ) >> 3) & 7)) << 2) | (t & 3);

    // Swizzled read addresses: logical window starts at W0 = 8g + 8h + dbase
    // (granule-aligned); 4 granules cover the 16-float window.
    int ra[4];
#pragma unroll
    for (int k = 0; k < 4; ++k) {
        const int G = 2 * g + 2 * h + (dhalf << 3) + k;
        ra[k] = (G ^ ((G >> 3) & 7)) << 2;
    }

    float acc[9][8];
#pragma unroll
    for (int dd = 0; dd < 9; ++dd)
#pragma unroll
        for (int xi = 0; xi < 8; ++xi) acc[dd][xi] = 0.f;

    // x1 staging columns for logical lds indices t, t+256, t+512
    const int c0 = t - 32;         // [-32, 223]
    const int c1 = t + 224;        // [224, 479] always valid
    const int c2 = t + 480;        // [480, 543] valid iff < 512 (t < 32)

    // prefetch channel 0
    float v0 = (c0 >= 0) ? x1row[c0] : 0.f;
    float v1 = x1row[c1];
    float v2 = (t < 32) ? x1row[c2] : 0.f;
    float4 xa = *(const float4*)(x0row + 8 * g);
    float4 xb = *(const float4*)(x0row + 8 * g + 4);

#pragma unroll 1
    for (int c = 0; c < CF; ++c) {
        __syncthreads();                       // prior readers done
        lds1[wa0] = v0;
        lds1[wa1] = v1;
        if (t < 64) lds1[wa2] = v2;
        __syncthreads();                       // row c staged

        const float x0v[8] = {xa.x, xa.y, xa.z, xa.w, xb.x, xb.y, xb.z, xb.w};

        if (c + 1 < CF) {                      // prefetch next channel
            const float* xr = x1row + (size_t)(c + 1) * CH;
            v0 = (c0 >= 0) ? xr[c0] : 0.f;
            v1 = xr[c1];
            v2 = (t < 32) ? xr[c2] : 0.f;
            const float* x0n = x0row + (size_t)(c + 1) * CH + 8 * g;
            xa = *(const float4*)x0n;
            xb = *(const float4*)(x0n + 4);
        }

        // 16-float window via 4 swizzled ds_read_b128
        float w[16];
#pragma unroll
        for (int k = 0; k < 4; ++k) {
            const float4 r = *(const float4*)&lds1[ra[k]];
            w[4 * k + 0] = r.x; w[4 * k + 1] = r.y;
            w[4 * k + 2] = r.z; w[4 * k + 3] = r.w;
        }
#pragma unroll
        for (int dd = 0; dd < 9; ++dd) {
            if (dd < nd) {                     // wave-uniform
#pragma unroll
                for (int xi = 0; xi < 8; ++xi)
                    acc[dd][xi] = fmaf(x0v[xi], w[dd + xi], acc[dd][xi]);
            }
        }
    }

    // Horizontal 3-sum via intra-wave shuffles (col neighbors are lane +-1).
    float* wsb = ws + (size_t)b * wsBStride;
#pragma unroll
    for (int dd = 0; dd < 9; ++dd) {
        if (dd < nd) {                         // wave-uniform -> shfl safe
            float left  = __shfl_up(acc[dd][7], 1);
            if (g == 0)  left = 0.f;           // col -1 is zero-pad
            float right = __shfl_down(acc[dd][0], 1);
            if (g == 63) right = 0.f;          // col 512 is zero-pad
            float r[8];
            r[0] = left + acc[dd][0] + acc[dd][1];
#pragma unroll
            for (int xi = 1; xi < 7; ++xi)
                r[xi] = acc[dd][xi - 1] + acc[dd][xi] + acc[dd][xi + 1];
            r[7] = acc[dd][6] + acc[dd][7] + right;

            const int d = dbase + 8 * h + dd;
            float* dst = wsb + ((size_t)d * HF + y) * WF + 8 * g;
            *(float4*)dst       = make_float4(r[0], r[1], r[2], r[3]);
            *(float4*)(dst + 4) = make_float4(r[4], r[5], r[6], r[7]);
        }
    }
}

// ---------------------------------------------------------------------------
// k2: vertical 3-sum + scale: out[d][i][j] = INV * (r[i-1] + r[i] + r[i+1])
// grid: (8 rowgroups, D, B); block 256 = 2 chains x 128 float4-columns.
// ---------------------------------------------------------------------------
__global__ __launch_bounds__(256)
void corr_vsum(const float* __restrict__ ws, float* __restrict__ out,
               size_t wsBStride, size_t outBStride) {
    const int t = threadIdx.x;
    const int chain = t >> 7;             // 0,1
    const int j = (t & 127) * 4;
    const int r0 = blockIdx.x * 32 + chain * 16;
    const int d = blockIdx.y;
    const int b = blockIdx.z;

    const float* wp = ws + (size_t)b * wsBStride + (size_t)d * WH + j;
    float* op       = out + (size_t)b * outBStride + (size_t)d * WH + j;

    float4 prev, cur;
    if (r0 > 0) prev = *(const float4*)(wp + (size_t)(r0 - 1) * WF);
    else        prev = make_float4(0.f, 0.f, 0.f, 0.f);
    cur = *(const float4*)(wp + (size_t)r0 * WF);

#pragma unroll
    for (int i = 0; i < 16; ++i) {
        const int r = r0 + i;
        float4 nx;
        if (r + 1 < HF) nx = *(const float4*)(wp + (size_t)(r + 1) * WF);
        else            nx = make_float4(0.f, 0.f, 0.f, 0.f);
        float4 o;
        o.x = (prev.x + cur.x + nx.x) * INV;
        o.y = (prev.y + cur.y + nx.y) * INV;
        o.z = (prev.z + cur.z + nx.z) * INV;
        o.w = (prev.w + cur.w + nx.w) * INV;
        *(float4*)(op + (size_t)r * WF) = o;
        prev = cur; cur = nx;
    }
}

// ---------------------------------------------------------------------------
// Emergency fallback (tiny ws): direct computation, slow but correct.
// ---------------------------------------------------------------------------
__global__ void corr_naive(const float* __restrict__ x0, const float* __restrict__ x1,
                           float* __restrict__ out) {
    const size_t total = (size_t)4 * NDTOT * WH;
    size_t idx = (size_t)blockIdx.x * blockDim.x + threadIdx.x;
    if (idx >= total) return;
    const int j = (int)(idx % WF);
    const int i = (int)((idx / WF) % HF);
    const int d = (int)((idx / WH) % NDTOT);
    const int b = (int)(idx / ((size_t)NDTOT * WH));
    const int disp = d - 32;
    float s = 0.f;
    for (int u = i - 1; u <= i + 1; ++u) {
        if (u < 0 || u >= HF) continue;
        for (int v = j - 1; v <= j + 1; ++v) {
            if (v < 0 || v >= WF) continue;
            const int v1c = v + disp;
            if (v1c < 0 || v1c >= WF) continue;
            const float* p0 = x0 + (size_t)b * CF * CH + (size_t)u * WF + v;
            const float* p1 = x1 + (size_t)b * CF * CH + (size_t)u * WF + v1c;
            for (int c = 0; c < CF; ++c)
                s += p0[(size_t)c * CH] * p1[(size_t)c * CH];
        }
    }
    out[idx] = s * INV;
}

// ---------------------------------------------------------------------------
extern "C" void kernel_launch(void* const* d_in, const int* in_sizes, int n_in,
                              void* d_out, int out_size, void* d_ws, size_t ws_size,
                              hipStream_t stream) {
    const float* x0 = (const float*)d_in[0];
    const float* x1 = (const float*)d_in[1];
    float* out = (float*)d_out;
    float* ws  = (float*)d_ws;

    const size_t fullB = (size_t)NDTOT * WH;     // per-b ws elements

    if (ws_size >= 4 * fullB * sizeof(float)) {
        corr_rows<<<dim3(2, 256, 4), dim3(256), 0, stream>>>(x0, x1, ws, fullB);
        corr_vsum<<<dim3(8, 65, 4), dim3(256), 0, stream>>>(ws, out, fullB, fullB);
    } else if (ws_size >= fullB * sizeof(float)) {
        for (int b = 0; b < 4; ++b) {
            const float* x0b = x0 + (size_t)b * CF * CH;
            const float* x1b = x1 + (size_t)b * CF * CH;
            float* outb = out + (size_t)b * fullB;
            corr_rows<<<dim3(2, 256, 1), dim3(256), 0, stream>>>(x0b, x1b, ws, 0);
            corr_vsum<<<dim3(8, 65, 1), dim3(256), 0, stream>>>(ws, outb, 0, 0);
        }
    } else {
        const size_t total = (size_t)4 * NDTOT * WH;
        const int blocks = (int)((total + 255) / 256);
        corr_naive<<<dim3(blocks), dim3(256), 0, stream>>>(x0, x1, out);
    }
}

// Round 4
// 241.441 us; speedup vs baseline: 1.1858x; 1.1858x over previous
//
#include <hip/hip_runtime.h>

#define WF 512
#define HF 256
#define CF 64
#define NDTOT 65

static constexpr size_t CH  = (size_t)HF * WF;   // one channel plane (elements)
static constexpr size_t WH  = (size_t)HF * WF;   // one (b,d) output plane (elements)
static constexpr float  INV = 1.0f / 576.0f;     // 1/(K*K*C)

typedef __attribute__((address_space(3))) void lds_void_t;
typedef const __attribute__((address_space(1))) void glb_void_t;

// ---------------------------------------------------------------------------
// k1: per (b, y, dblock) — horizontally box-summed channel-dot rows.
//   r[d][x] = sum_{v=x-1..x+1} sum_c x0[b,c,y,v] * x1[b,c,y,v+d-32]
// 256 threads = 4 waves. Thread tile: 8 cols x 9 d, ALL static (no guards in
// the c-loop; the 9th d is redundant except wave 3 of dblock 1 -> d=64).
// x1 row staged via global_load_lds (16B) into double-buffered, granule-XOR
// swizzled LDS (linear DMA dest + inverse-swizzled per-lane global source).
// Pad granules (cols -32..-1, 512..543) zeroed once; DMA never touches them.
// ---------------------------------------------------------------------------
__global__ __launch_bounds__(256) __attribute__((amdgpu_waves_per_eu(2, 4)))
void corr_rows(const float* __restrict__ x0, const float* __restrict__ x1,
               float* __restrict__ ws) {
    __shared__ float4 bufA[144];
    __shared__ float4 bufB[144];

    // XCD-pair swizzle: the (dblock 0,1) pair of one (b,y) lands on one XCD.
    const int f = blockIdx.x;              // [0, 2048)
    const int xcd = f & 7;
    const int rr = f >> 3;                 // [0, 256)
    const int dblock = rr & 1;
    const int pair = (xcd << 7) | (rr >> 1);   // [0, 1024)
    const int y = pair & 255;
    const int b = pair >> 8;

    const int t = threadIdx.x;
    const int g = t & 63;                  // col-group (lane): cols 8g..8g+7
    const int h = t >> 6;                  // d-group (wave):  d = 32*dblock+8h+dd

    const float* x0row = x0 + (size_t)b * CF * CH + (size_t)y * WF;
    const float* x1row = x1 + (size_t)b * CF * CH + (size_t)y * WF;

    // Zero the pad granules once (they are fixed points of the swizzle's sets).
    if (t < 32) {
        int gi = t & 15;
        gi = (gi < 8) ? gi : (gi + 128);   // granules 0..7 and 136..143
        if (t < 16) bufA[gi] = make_float4(0.f, 0.f, 0.f, 0.f);
        else        bufB[gi] = make_float4(0.f, 0.f, 0.f, 0.f);
    }

    // DMA staging: waves 0,1 fill physical granules [8,72) / [72,136).
    // Linear LDS dest (base + lane*16); per-lane global source inverse-swizzled.
    const int Pbase = (h & 1) ? 72 : 8;
    const int P = Pbase + g;                       // physical granule
    const int L = P ^ ((P >> 3) & 7);              // logical granule (involution)
    const float* dmasrc = x1row + 4 * L - 32;      // logical float L*4 - 32 = col
    float4* dstA = bufA + Pbase;                   // wave-uniform dest base
    float4* dstB = bufB + Pbase;

#define STAGE(cc, DST) \
    do { if (h < 2) __builtin_amdgcn_global_load_lds( \
            (glb_void_t*)(dmasrc + (size_t)(cc) * CH), (lds_void_t*)(DST), 16, 0, 0); } while (0)

    // Swizzled window-read granules: logical window base float = 8g+8h+32*dblock.
    const int Gb = 2 * g + 2 * h + (dblock << 3);
    const int G0 = Gb, G1 = Gb + 1, G2 = Gb + 2, G3 = Gb + 3;
    const int ra0 = G0 ^ ((G0 >> 3) & 7);
    const int ra1 = G1 ^ ((G1 >> 3) & 7);
    const int ra2 = G2 ^ ((G2 >> 3) & 7);
    const int ra3 = G3 ^ ((G3 >> 3) & 7);

    float acc[9][8];
#pragma unroll
    for (int dd = 0; dd < 9; ++dd)
#pragma unroll
        for (int xi = 0; xi < 8; ++xi) acc[dd][xi] = 0.f;

    const float* x0g = x0row + 8 * g;
    float4 xa = *(const float4*)(x0g);
    float4 xb = *(const float4*)(x0g + 4);
    float4 xan, xbn;

    STAGE(0, dstA);
    __syncthreads();   // barrier drains vmcnt: DMA + x0 loads landed

#define ITER(CBUF, NDST, cc) \
    do { \
        const float4 wv0 = CBUF[ra0]; \
        const float4 wv1 = CBUF[ra1]; \
        const float4 wv2 = CBUF[ra2]; \
        const float4 wv3 = CBUF[ra3]; \
        if ((cc) + 1 < CF) STAGE((cc) + 1, NDST); \
        { const size_t cn = (size_t)(((cc) + 1 < CF) ? (cc) + 1 : CF - 1) * CH; \
          xan = *(const float4*)(x0g + cn); \
          xbn = *(const float4*)(x0g + cn + 4); } \
        const float w[16] = {wv0.x, wv0.y, wv0.z, wv0.w, wv1.x, wv1.y, wv1.z, wv1.w, \
                             wv2.x, wv2.y, wv2.z, wv2.w, wv3.x, wv3.y, wv3.z, wv3.w}; \
        const float xv[8] = {xa.x, xa.y, xa.z, xa.w, xb.x, xb.y, xb.z, xb.w}; \
        _Pragma("unroll") \
        for (int dd = 0; dd < 9; ++dd) { \
            _Pragma("unroll") \
            for (int xi = 0; xi < 8; ++xi) \
                acc[dd][xi] = fmaf(xv[xi], w[dd + xi], acc[dd][xi]); \
        } \
        xa = xan; xb = xbn; \
        __syncthreads(); \
    } while (0)

#pragma unroll 1
    for (int c2 = 0; c2 < CF / 2; ++c2) {
        ITER(bufA, dstB, 2 * c2);
        ITER(bufB, dstA, 2 * c2 + 1);
    }

    // Horizontal 3-sum via intra-wave shuffles; cols are lane +-1 neighbors.
    float* wsb = ws + (size_t)b * NDTOT * WH;
    const int dbase = (dblock << 5) + (h << 3);

#define WRITE_DD(dd) \
    do { \
        float left  = __shfl_up(acc[dd][7], 1);   if (g == 0)  left  = 0.f; \
        float right = __shfl_down(acc[dd][0], 1); if (g == 63) right = 0.f; \
        const float r0 = left + acc[dd][0] + acc[dd][1]; \
        const float r1 = acc[dd][0] + acc[dd][1] + acc[dd][2]; \
        const float r2 = acc[dd][1] + acc[dd][2] + acc[dd][3]; \
        const float r3 = acc[dd][2] + acc[dd][3] + acc[dd][4]; \
        const float r4 = acc[dd][3] + acc[dd][4] + acc[dd][5]; \
        const float r5 = acc[dd][4] + acc[dd][5] + acc[dd][6]; \
        const float r6 = acc[dd][5] + acc[dd][6] + acc[dd][7]; \
        const float r7 = acc[dd][6] + acc[dd][7] + right; \
        float* dst = wsb + ((size_t)(dbase + (dd)) * HF + y) * WF + 8 * g; \
        *(float4*)dst       = make_float4(r0, r1, r2, r3); \
        *(float4*)(dst + 4) = make_float4(r4, r5, r6, r7); \
    } while (0)

#pragma unroll
    for (int dd = 0; dd < 8; ++dd) WRITE_DD(dd);
    if (dblock == 1 && h == 3) WRITE_DD(8);      // d = 64

#undef STAGE
#undef ITER
#undef WRITE_DD
}

// ---------------------------------------------------------------------------
// k2: vertical 3-sum + scale: out[d][i][j] = INV * (r[i-1] + r[i] + r[i+1])
// grid: (8 rowgroups, D, B); block 256 = 2 chains x 128 float4-columns.
// ---------------------------------------------------------------------------
__global__ __launch_bounds__(256)
void corr_vsum(const float* __restrict__ ws, float* __restrict__ out,
               size_t wsBStride, size_t outBStride) {
    const int t = threadIdx.x;
    const int chain = t >> 7;             // 0,1
    const int j = (t & 127) * 4;
    const int r0 = blockIdx.x * 32 + chain * 16;
    const int d = blockIdx.y;
    const int b = blockIdx.z;

    const float* wp = ws + (size_t)b * wsBStride + (size_t)d * WH + j;
    float* op       = out + (size_t)b * outBStride + (size_t)d * WH + j;

    float4 prev, cur;
    if (r0 > 0) prev = *(const float4*)(wp + (size_t)(r0 - 1) * WF);
    else        prev = make_float4(0.f, 0.f, 0.f, 0.f);
    cur = *(const float4*)(wp + (size_t)r0 * WF);

#pragma unroll
    for (int i = 0; i < 16; ++i) {
        const int r = r0 + i;
        float4 nx;
        if (r + 1 < HF) nx = *(const float4*)(wp + (size_t)(r + 1) * WF);
        else            nx = make_float4(0.f, 0.f, 0.f, 0.f);
        float4 o;
        o.x = (prev.x + cur.x + nx.x) * INV;
        o.y = (prev.y + cur.y + nx.y) * INV;
        o.z = (prev.z + cur.z + nx.z) * INV;
        o.w = (prev.w + cur.w + nx.w) * INV;
        *(float4*)(op + (size_t)r * WF) = o;
        prev = cur; cur = nx;
    }
}

// ---------------------------------------------------------------------------
// Emergency fallback (tiny ws): direct computation, slow but correct.
// ---------------------------------------------------------------------------
__global__ void corr_naive(const float* __restrict__ x0, const float* __restrict__ x1,
                           float* __restrict__ out) {
    const size_t total = (size_t)4 * NDTOT * WH;
    size_t idx = (size_t)blockIdx.x * blockDim.x + threadIdx.x;
    if (idx >= total) return;
    const int j = (int)(idx % WF);
    const int i = (int)((idx / WF) % HF);
    const int d = (int)((idx / WH) % NDTOT);
    const int b = (int)(idx / ((size_t)NDTOT * WH));
    const int disp = d - 32;
    float s = 0.f;
    for (int u = i - 1; u <= i + 1; ++u) {
        if (u < 0 || u >= HF) continue;
        for (int v = j - 1; v <= j + 1; ++v) {
            if (v < 0 || v >= WF) continue;
            const int v1c = v + disp;
            if (v1c < 0 || v1c >= WF) continue;
            const float* p0 = x0 + (size_t)b * CF * CH + (size_t)u * WF + v;
            const float* p1 = x1 + (size_t)b * CF * CH + (size_t)u * WF + v1c;
            for (int c = 0; c < CF; ++c)
                s += p0[(size_t)c * CH] * p1[(size_t)c * CH];
        }
    }
    out[idx] = s * INV;
}

// ---------------------------------------------------------------------------
extern "C" void kernel_launch(void* const* d_in, const int* in_sizes, int n_in,
                              void* d_out, int out_size, void* d_ws, size_t ws_size,
                              hipStream_t stream) {
    const float* x0 = (const float*)d_in[0];
    const float* x1 = (const float*)d_in[1];
    float* out = (float*)d_out;
    float* ws  = (float*)d_ws;

    const size_t fullB = (size_t)NDTOT * WH;     // per-b ws elements

    if (ws_size >= 4 * fullB * sizeof(float)) {
        corr_rows<<<dim3(2048), dim3(256), 0, stream>>>(x0, x1, ws);
        corr_vsum<<<dim3(8, 65, 4), dim3(256), 0, stream>>>(ws, out, fullB, fullB);
    } else {
        const size_t total = (size_t)4 * NDTOT * WH;
        const int blocks = (int)((total + 255) / 256);
        corr_naive<<<dim3(blocks), dim3(256), 0, stream>>>(x0, x1, out);
    }
}

// Round 5
// 189.275 us; speedup vs baseline: 1.5126x; 1.2756x over previous
//
#include <hip/hip_runtime.h>

#define WF 512
#define HF 256
#define CF 64
#define NDTOT 65
#define DP 72            // padded d-stride in ws (f16 elements), 144 B rows

static constexpr size_t CH  = (size_t)HF * WF;
static constexpr size_t WH  = (size_t)HF * WF;
static constexpr float  INV = 1.0f / 576.0f;

typedef _Float16 f16;
typedef _Float16 f16x2 __attribute__((ext_vector_type(2)));
typedef _Float16 f16x8 __attribute__((ext_vector_type(8)));
typedef float    f32x4 __attribute__((ext_vector_type(4)));

// ---------------------------------------------------------------------------
// k1: banded Gram via MFMA, fp16 hi/lo split (D = A*B in fp32 AGPRs).
// Per (b, y, strip of 128 x-cols): G[x,j] = sum_c x0[c,x]*x1[c,j] for
// j-x in [-32,32]; store as ws[b][y][x][d=j-x+32] (f16).
// 256 thr = 4 waves; wave w owns x-tiles {2w, 2w+1} x 5 j-offsets = 10 tiles.
// ---------------------------------------------------------------------------
__global__ __launch_bounds__(256)
void corr_gram(const float* __restrict__ x0, const float* __restrict__ x1,
               f16* __restrict__ ws) {
    const int strip = blockIdx.x;      // 0..3
    const int y = blockIdx.y;
    const int b = blockIdx.z;
    const int t = threadIdx.x;
    const int l = t & 63;
    const int w = t >> 6;
    const int xs = strip << 7;
    const int jb = xs - 32;

    // [tile][row 16][K-half 32 padded to 40] -> 80 B rows, conflict-free b128
    __shared__ f16 Ah[8][16][40];      // x0 hi   (10 KB)
    __shared__ f16 Al[8][16][40];      // x0 lo
    __shared__ f16 Bh[12][16][40];     // x1 hi   (15 KB)
    __shared__ f16 Bl[12][16][40];     // x1 lo   -> 50 KB total

    const float* x0r = x0 + (size_t)b * CF * CH + (size_t)y * WF;
    const float* x1r = x1 + (size_t)b * CF * CH + (size_t)y * WF;

    f32x4 acc[10];
#pragma unroll
    for (int i = 0; i < 10; ++i) acc[i] = (f32x4)0.0f;

    const int m_f = l & 15;            // fragment row (A) / col (B)
    const int ks  = (l >> 4) * 8;      // fragment k-start within 32-K half

#pragma unroll 1
    for (int hh = 0; hh < 2; ++hh) {   // two K-halves of 32 channels
        __syncthreads();               // prior compute done before overwrite

        // ---- stage A (x0 strip): 128 cols x 32 ch, hi/lo ----
#pragma unroll
        for (int chunk = 0; chunk < 2; ++chunk) {
#pragma unroll
            for (int k = 0; k < 4; ++k) {
                const int cpL = k * 4 + w;                 // local c-pair 0..15
                const int c = hh * 32 + cpL * 2;
                const int lx = chunk * 64 + l;
                const float f0 = x0r[(size_t)c * CH + xs + lx];
                const float f1 = x0r[(size_t)(c + 1) * CH + xs + lx];
                const f16 h0 = (f16)f0; const f16 lo0 = (f16)(f0 - (float)h0);
                const f16 h1 = (f16)f1; const f16 lo1 = (f16)(f1 - (float)h1);
                const int xt = lx >> 4, m = lx & 15;
                *(f16x2*)&Ah[xt][m][cpL * 2] = (f16x2){h0, h1};
                *(f16x2*)&Al[xt][m][cpL * 2] = (f16x2){lo0, lo1};
            }
        }
        // ---- stage B (x1 strip): 192 cols x 32 ch, hi/lo, OOB -> 0 ----
#pragma unroll
        for (int chunk = 0; chunk < 3; ++chunk) {
#pragma unroll
            for (int k = 0; k < 4; ++k) {
                const int cpL = k * 4 + w;
                const int c = hh * 32 + cpL * 2;
                const int lj = chunk * 64 + l;
                const int j = jb + lj;
                const bool ok = (unsigned)j < (unsigned)WF;
                const float f0 = ok ? x1r[(size_t)c * CH + j] : 0.f;
                const float f1 = ok ? x1r[(size_t)(c + 1) * CH + j] : 0.f;
                const f16 h0 = (f16)f0; const f16 lo0 = (f16)(f0 - (float)h0);
                const f16 h1 = (f16)f1; const f16 lo1 = (f16)(f1 - (float)h1);
                const int jt = lj >> 4, n = lj & 15;
                *(f16x2*)&Bh[jt][n][cpL * 2] = (f16x2){h0, h1};
                *(f16x2*)&Bl[jt][n][cpL * 2] = (f16x2){lo0, lo1};
            }
        }
        __syncthreads();

        // ---- compute: 30 MFMAs per wave per half ----
        const f16x8 a_h0 = *(const f16x8*)&Ah[2 * w][m_f][ks];
        const f16x8 a_h1 = *(const f16x8*)&Ah[2 * w + 1][m_f][ks];
        const f16x8 a_l0 = *(const f16x8*)&Al[2 * w][m_f][ks];
        const f16x8 a_l1 = *(const f16x8*)&Al[2 * w + 1][m_f][ks];
        f16x8 b_h[6], b_l[6];
#pragma unroll
        for (int p6 = 0; p6 < 6; ++p6) {
            b_h[p6] = *(const f16x8*)&Bh[2 * w + p6][m_f][ks];
            b_l[p6] = *(const f16x8*)&Bl[2 * w + p6][m_f][ks];
        }
#pragma unroll
        for (int p = 0; p < 5; ++p) {
            acc[p] = __builtin_amdgcn_mfma_f32_16x16x32_f16(a_h0, b_h[p], acc[p], 0, 0, 0);
            acc[p] = __builtin_amdgcn_mfma_f32_16x16x32_f16(a_h0, b_l[p], acc[p], 0, 0, 0);
            acc[p] = __builtin_amdgcn_mfma_f32_16x16x32_f16(a_l0, b_h[p], acc[p], 0, 0, 0);
        }
#pragma unroll
        for (int p = 0; p < 5; ++p) {
            acc[5 + p] = __builtin_amdgcn_mfma_f32_16x16x32_f16(a_h1, b_h[p + 1], acc[5 + p], 0, 0, 0);
            acc[5 + p] = __builtin_amdgcn_mfma_f32_16x16x32_f16(a_h1, b_l[p + 1], acc[5 + p], 0, 0, 0);
            acc[5 + p] = __builtin_amdgcn_mfma_f32_16x16x32_f16(a_l1, b_h[p + 1], acc[5 + p], 0, 0, 0);
        }
    }

    // ---- epilogue: band store. C/D layout: col n = l&15, row m = (l>>4)*4+q ----
    f16* wsrow = ws + ((size_t)(b * HF + y) * WF) * DP;
    const int n = l & 15;
#pragma unroll
    for (int xtl = 0; xtl < 2; ++xtl) {
#pragma unroll
        for (int p = 0; p < 5; ++p) {
            const int i = xtl * 5 + p;
#pragma unroll
            for (int q = 0; q < 4; ++q) {
                const int m = (l >> 4) * 4 + q;
                const int x = xs + (2 * w + xtl) * 16 + m;
                const int d = 16 * p + n - m;
                if ((unsigned)d < (unsigned)NDTOT)
                    wsrow[(size_t)x * DP + d] = (f16)acc[i][q];
            }
        }
    }
}

// ---------------------------------------------------------------------------
// k2: 3x3 box-sum over ws + scale: out[b,d,y,x] = INV * sum_{3x3} ws[y+dy][x+dx][d]
// grid (16 x-tiles of 32, 32 y-tiles of 8, b); 256 thr.
// ---------------------------------------------------------------------------
__global__ __launch_bounds__(256)
void corr_box(const f16* __restrict__ ws, float* __restrict__ out) {
    const int xt = blockIdx.x;
    const int yt = blockIdx.y;
    const int b = blockIdx.z;
    const int t = threadIdx.x;
    const int x0b = xt * 32, y0 = yt * 8;

    __shared__ f16 S[10 * 34][DP];     // 48.96 KB

    // stage (y0-1..y0+8) x (x0b-1..x0b+32) x 72d, OOB -> 0
    for (int u = 0; u < 10; ++u) {
        const int yy = y0 - 1 + u;
        const bool yok = (unsigned)yy < (unsigned)HF;
        const f16* src = ws + ((size_t)(b * HF + yy) * WF + (x0b - 1)) * DP;
#pragma unroll
        for (int sub = 0; sub < 2; ++sub) {
            const int idx = sub * 256 + t;
            if (idx < 306) {
                const int v = idx / 9, dg = idx - v * 9;
                const int xx = x0b - 1 + v;
                f16x8 val;
#pragma unroll
                for (int jj = 0; jj < 8; ++jj) val[jj] = (f16)0.f;
                if (yok && (unsigned)xx < (unsigned)WF)
                    val = *(const f16x8*)(src + (size_t)v * DP + dg * 8);
                *(f16x8*)&S[u * 34 + v][dg * 8] = val;
            }
        }
    }
    __syncthreads();

    const int ly = t >> 5, lx = t & 31;
    const int yg = y0 + ly, xg = x0b + lx;
    float* o0 = out + (size_t)b * NDTOT * WH + (size_t)yg * WF + xg;

#pragma unroll 1
    for (int dg = 0; dg < 9; ++dg) {
        f16x8 s;
#pragma unroll
        for (int jj = 0; jj < 8; ++jj) s[jj] = (f16)0.f;
#pragma unroll
        for (int du = 0; du < 3; ++du)
#pragma unroll
            for (int dv = 0; dv < 3; ++dv)
                s += *(const f16x8*)&S[(ly + du) * 34 + (lx + dv)][dg * 8];
#pragma unroll
        for (int jj = 0; jj < 8; ++jj) {
            const int d = dg * 8 + jj;
            if (d < NDTOT) o0[(size_t)d * WH] = (float)s[jj] * INV;
        }
    }
}

// ---------------------------------------------------------------------------
// Emergency fallback (tiny ws): direct computation, slow but correct.
// ---------------------------------------------------------------------------
__global__ void corr_naive(const float* __restrict__ x0, const float* __restrict__ x1,
                           float* __restrict__ out) {
    const size_t total = (size_t)4 * NDTOT * WH;
    size_t idx = (size_t)blockIdx.x * blockDim.x + threadIdx.x;
    if (idx >= total) return;
    const int j = (int)(idx % WF);
    const int i = (int)((idx / WF) % HF);
    const int d = (int)((idx / WH) % NDTOT);
    const int b = (int)(idx / ((size_t)NDTOT * WH));
    const int disp = d - 32;
    float s = 0.f;
    for (int u = i - 1; u <= i + 1; ++u) {
        if (u < 0 || u >= HF) continue;
        for (int v = j - 1; v <= j + 1; ++v) {
            if (v < 0 || v >= WF) continue;
            const int v1c = v + disp;
            if (v1c < 0 || v1c >= WF) continue;
            const float* p0 = x0 + (size_t)b * CF * CH + (size_t)u * WF + v;
            const float* p1 = x1 + (size_t)b * CF * CH + (size_t)u * WF + v1c;
            for (int c = 0; c < CF; ++c)
            s += p0[(size_t)c * CH] * p1[(size_t)c * CH];
    }
    }
    out[idx] = s * INV;
}

// ---------------------------------------------------------------------------
extern "C" void kernel_launch(void* const* d_in, const int* in_sizes, int n_in,
                              void* d_out, int out_size, void* d_ws, size_t ws_size,
                              hipStream_t stream) {
    const float* x0 = (const float*)d_in[0];
    const float* x1 = (const float*)d_in[1];
    float* out = (float*)d_out;

    const size_t wsNeed = (size_t)4 * HF * WF * DP * sizeof(f16);  // 75.5 MB

    if (ws_size >= wsNeed) {
        f16* ws = (f16*)d_ws;
        corr_gram<<<dim3(4, 256, 4), dim3(256), 0, stream>>>(x0, x1, ws);
        corr_box<<<dim3(16, 32, 4), dim3(256), 0, stream>>>(ws, out);
    } else {
        const size_t total = (size_t)4 * NDTOT * WH;
        const int blocks = (int)((total + 255) / 256);
        corr_naive<<<dim3(blocks), dim3(256), 0, stream>>>(x0, x1, out);
    }
}

// Round 6
// 155.488 us; speedup vs baseline: 1.8413x; 1.2173x over previous
//
#include <hip/hip_runtime.h>

#define WF 512
#define HF 256
#define CF 64
#define NDTOT 65
#define DP 72            // padded d-stride in ws (f16 elements), 144 B rows

static constexpr size_t CH  = (size_t)HF * WF;
static constexpr size_t WH  = (size_t)HF * WF;
static constexpr float  INV = 1.0f / 576.0f;

typedef _Float16 f16;
typedef _Float16 f16x8 __attribute__((ext_vector_type(8)));
typedef float    f32x4 __attribute__((ext_vector_type(4)));

// ---------------------------------------------------------------------------
// k1: banded Gram via MFMA, fp16 hi/lo split (hh + hl + lh), LDS-FREE.
// Per (b, y, strip of 128 x-cols): G[x,j] = sum_c x0[c,x]*x1[c,j],
// j-x in [-32,32]; stored ws[b][y][x][d=j-x+32] (f16).
// 256 thr = 4 waves; wave w owns x-tiles {2w,2w+1} x 5 j-offsets = 10 acc.
// Fragments loaded DIRECTLY from global into registers (coalesced 64B
// segments, 16 lanes/col-run); all raw loads of a group issued before any
// convert -> deep MLP, no barriers, no LDS.
// A-frag: lane l: col = tile*16 + (l&15), k(=channel) = hh*32+(l>>4)*8+i.
// B-frag: lane l: j   = jb + jt*16 + (l&15), same k. (layout validated R5)
// ---------------------------------------------------------------------------
__global__ __launch_bounds__(256)
void corr_gram(const float* __restrict__ x0, const float* __restrict__ x1,
               f16* __restrict__ ws) {
    // XCD swizzle: all 4 strips of one (b,y) on one XCD, dispatched adjacently.
    const int f = blockIdx.x;              // [0, 4096)
    const int xcd = f & 7;
    const int strip = (f >> 3) & 3;
    const int pl = f >> 5;                 // [0, 128)
    const int pair = xcd * 128 + pl;       // [0, 1024)
    const int y = pair & 255;
    const int b = pair >> 8;

    const int t = threadIdx.x;
    const int l = t & 63;
    const int w = t >> 6;
    const int xs = strip << 7;
    const int jb = xs - 32;

    const int n  = l & 15;                 // fragment row/col index
    const int ks = (l >> 4) * 8;           // fragment k-start

    const float* x0r = x0 + (size_t)b * CF * CH + (size_t)y * WF;
    const float* x1r = x1 + (size_t)b * CF * CH + (size_t)y * WF;

    const int colA = xs + 2 * w * 16 + n;  // a0 col; a1 = +16

    f32x4 acc[10];
#pragma unroll
    for (int i = 0; i < 10; ++i) acc[i] = (f32x4)0.0f;

#pragma unroll
    for (int hh = 0; hh < 2; ++hh) {
        const size_t cb = (size_t)(hh * 32 + ks) * CH;

        // ---- A: issue all 16 raw loads, then convert ----
        float ar0[8], ar1[8];
        const float* pA = x0r + cb + colA;
#pragma unroll
        for (int i = 0; i < 8; ++i) ar0[i] = pA[(size_t)i * CH];
#pragma unroll
        for (int i = 0; i < 8; ++i) ar1[i] = pA[(size_t)i * CH + 16];
        f16x8 ah0, ah1, al0, al1;
#pragma unroll
        for (int i = 0; i < 8; ++i) {
            const f16 h0 = (f16)ar0[i]; ah0[i] = h0; al0[i] = (f16)(ar0[i] - (float)h0);
            const f16 h1 = (f16)ar1[i]; ah1[i] = h1; al1[i] = (f16)(ar1[i] - (float)h1);
        }

        // ---- B: two groups of 3 fragments (caps live registers) ----
#pragma unroll
        for (int g2 = 0; g2 < 2; ++g2) {
            float br[3][8];
#pragma unroll
            for (int k3 = 0; k3 < 3; ++k3) {
                const int jt = 2 * w + 3 * g2 + k3;
                const int j = jb + jt * 16 + n;
                const bool ok = (unsigned)j < (unsigned)WF;
                const float* pB = x1r + cb + j;
#pragma unroll
                for (int i = 0; i < 8; ++i)
                    br[k3][i] = ok ? pB[(size_t)i * CH] : 0.f;
            }
            f16x8 bh[3], bl[3];
#pragma unroll
            for (int k3 = 0; k3 < 3; ++k3)
#pragma unroll
                for (int i = 0; i < 8; ++i) {
                    const f16 h = (f16)br[k3][i];
                    bh[k3][i] = h;
                    bl[k3][i] = (f16)(br[k3][i] - (float)h);
                }

#define TRIPLE(ai, AH, AL, bi) \
    do { \
        acc[ai] = __builtin_amdgcn_mfma_f32_16x16x32_f16(AH, bh[bi], acc[ai], 0, 0, 0); \
        acc[ai] = __builtin_amdgcn_mfma_f32_16x16x32_f16(AH, bl[bi], acc[ai], 0, 0, 0); \
        acc[ai] = __builtin_amdgcn_mfma_f32_16x16x32_f16(AL, bh[bi], acc[ai], 0, 0, 0); \
    } while (0)

            if (g2 == 0) {
                TRIPLE(0, ah0, al0, 0);
                TRIPLE(1, ah0, al0, 1);
                TRIPLE(2, ah0, al0, 2);
                TRIPLE(5, ah1, al1, 1);
                TRIPLE(6, ah1, al1, 2);
            } else {
                TRIPLE(3, ah0, al0, 0);
                TRIPLE(4, ah0, al0, 1);
                TRIPLE(7, ah1, al1, 0);
                TRIPLE(8, ah1, al1, 1);
                TRIPLE(9, ah1, al1, 2);
            }
#undef TRIPLE
        }
    }

    // ---- epilogue: band store (layout validated R5).
    // C/D: col n = l&15, row m = (l>>4)*4+q ----
    f16* wsrow = ws + ((size_t)(b * HF + y) * WF) * DP;
#pragma unroll
    for (int xtl = 0; xtl < 2; ++xtl) {
#pragma unroll
        for (int p = 0; p < 5; ++p) {
            const int i = xtl * 5 + p;
#pragma unroll
            for (int q = 0; q < 4; ++q) {
                const int m = (l >> 4) * 4 + q;
                const int x = xs + (2 * w + xtl) * 16 + m;
                const int d = 16 * p + n - m;
                if ((unsigned)d < (unsigned)NDTOT)
                    wsrow[(size_t)x * DP + d] = (f16)acc[i][q];
            }
        }
    }
}

// ---------------------------------------------------------------------------
// k2: 3x3 box-sum over ws + scale: out[b,d,y,x] = INV * sum_{3x3} ws[y+dy][x+dx][d]
// grid (16 x-tiles of 32, 32 y-tiles of 8, b); 256 thr.
// ---------------------------------------------------------------------------
__global__ __launch_bounds__(256)
void corr_box(const f16* __restrict__ ws, float* __restrict__ out) {
    const int xt = blockIdx.x;
    const int yt = blockIdx.y;
    const int b = blockIdx.z;
    const int t = threadIdx.x;
    const int x0b = xt * 32, y0 = yt * 8;

    __shared__ f16 S[10 * 34][DP];     // 48.96 KB

    // stage (y0-1..y0+8) x (x0b-1..x0b+32) x 72d, OOB -> 0
    for (int u = 0; u < 10; ++u) {
        const int yy = y0 - 1 + u;
        const bool yok = (unsigned)yy < (unsigned)HF;
        const f16* src = ws + ((size_t)(b * HF + yy) * WF + (x0b - 1)) * DP;
#pragma unroll
        for (int sub = 0; sub < 2; ++sub) {
            const int idx = sub * 256 + t;
            if (idx < 306) {
                const int v = idx / 9, dg = idx - v * 9;
                const int xx = x0b - 1 + v;
                f16x8 val;
#pragma unroll
                for (int jj = 0; jj < 8; ++jj) val[jj] = (f16)0.f;
                if (yok && (unsigned)xx < (unsigned)WF)
                    val = *(const f16x8*)(src + (size_t)v * DP + dg * 8);
                *(f16x8*)&S[u * 34 + v][dg * 8] = val;
            }
        }
    }
    __syncthreads();

    const int ly = t >> 5, lx = t & 31;
    const int yg = y0 + ly, xg = x0b + lx;
    float* o0 = out + (size_t)b * NDTOT * WH + (size_t)yg * WF + xg;

#pragma unroll 1
    for (int dg = 0; dg < 9; ++dg) {
        f16x8 s;
#pragma unroll
        for (int jj = 0; jj < 8; ++jj) s[jj] = (f16)0.f;
#pragma unroll
        for (int du = 0; du < 3; ++du)
#pragma unroll
            for (int dv = 0; dv < 3; ++dv)
                s += *(const f16x8*)&S[(ly + du) * 34 + (lx + dv)][dg * 8];
#pragma unroll
        for (int jj = 0; jj < 8; ++jj) {
            const int d = dg * 8 + jj;
            if (d < NDTOT) o0[(size_t)d * WH] = (float)s[jj] * INV;
        }
    }
}

// ---------------------------------------------------------------------------
// Emergency fallback (tiny ws): direct computation, slow but correct.
// ---------------------------------------------------------------------------
__global__ void corr_naive(const float* __restrict__ x0, const float* __restrict__ x1,
                           float* __restrict__ out) {
    const size_t total = (size_t)4 * NDTOT * WH;
    size_t idx = (size_t)blockIdx.x * blockDim.x + threadIdx.x;
    if (idx >= total) return;
    const int j = (int)(idx % WF);
    const int i = (int)((idx / WF) % HF);
    const int d = (int)((idx / WH) % NDTOT);
    const int b = (int)(idx / ((size_t)NDTOT * WH));
    const int disp = d - 32;
    float s = 0.f;
    for (int u = i - 1; u <= i + 1; ++u) {
        if (u < 0 || u >= HF) continue;
        for (int v = j - 1; v <= j + 1; ++v) {
            if (v < 0 || v >= WF) continue;
            const int v1c = v + disp;
            if (v1c < 0 || v1c >= WF) continue;
            const float* p0 = x0 + (size_t)b * CF * CH + (size_t)u * WF + v;
            const float* p1 = x1 + (size_t)b * CF * CH + (size_t)u * WF + v1c;
            for (int c = 0; c < CF; ++c)
                s += p0[(size_t)c * CH] * p1[(size_t)c * CH];
        }
    }
    out[idx] = s * INV;
}

// ---------------------------------------------------------------------------
extern "C" void kernel_launch(void* const* d_in, const int* in_sizes, int n_in,
                              void* d_out, int out_size, void* d_ws, size_t ws_size,
                              hipStream_t stream) {
    const float* x0 = (const float*)d_in[0];
    const float* x1 = (const float*)d_in[1];
    float* out = (float*)d_out;

    const size_t wsNeed = (size_t)4 * HF * WF * DP * sizeof(f16);  // 75.5 MB

    if (ws_size >= wsNeed) {
        f16* ws = (f16*)d_ws;
        corr_gram<<<dim3(4096), dim3(256), 0, stream>>>(x0, x1, ws);
        corr_box<<<dim3(16, 32, 4), dim3(256), 0, stream>>>(ws, out);
    } else {
        const size_t total = (size_t)4 * NDTOT * WH;
        const int blocks = (int)((total + 255) / 256);
        corr_naive<<<dim3(blocks), dim3(256), 0, stream>>>(x0, x1, out);
    }
}

// Round 7
// 136.870 us; speedup vs baseline: 2.0917x; 1.1360x over previous
//
#include <hip/hip_runtime.h>

#define WF 512
#define HF 256
#define CF 64
#define NDTOT 65
#define DP 72            // padded d-stride in ws (f16 elements), 144 B rows

static constexpr size_t CH  = (size_t)HF * WF;
static constexpr size_t WH  = (size_t)HF * WF;
static constexpr float  INV = 1.0f / 576.0f;

typedef _Float16 f16;
typedef _Float16 f16x8 __attribute__((ext_vector_type(8)));
typedef float    f32x4 __attribute__((ext_vector_type(4)));

typedef __attribute__((address_space(3))) void lds_void_t;
typedef const __attribute__((address_space(1))) void glb_void_t;

// ---------------------------------------------------------------------------
// k1: banded Gram via MFMA, fp16 hi/lo split (hh + hl + lh).
// Per (b, y, strip of 128 x-cols): G[x,j] = sum_c x0[c,x]*x1[c,j],
// j-x in [-32,32]; stored ws[b][y][x][d=j-x+32] (f16).
// Data path: per 32-ch K-half, x0(128 cols) + x1(192 cols) staged RAW f32
// into 40 KB LDS via global_load_lds 16B DMAs (10/thread), granule-XOR
// swizzled (P = G ^ (((G>>8)&3)<<2)): inverse swizzle on the per-lane DMA
// SOURCE, forward on the ds_read — fragment reads are 2-way conflicts (free).
// x1 OOB cols: DMA source clamped, value zeroed at read.
// MFMA tiling (validated R5/R6): 4 waves; wave w: x-tiles {2w,2w+1} x
// j-tiles {2w..2w+5} -> 10 accs; A-frag lane l: col=tile*16+(l&15),
// k=(l>>4)*8+i.  Epilogue band-store unchanged.
// ---------------------------------------------------------------------------
__global__ __launch_bounds__(256, 4)
void corr_gram(const float* __restrict__ x0, const float* __restrict__ x1,
               f16* __restrict__ ws) {
    // XCD swizzle: all 4 strips of one (b,y) on one XCD, dispatched adjacently.
    const int f = blockIdx.x;              // [0, 4096)
    const int xcd = f & 7;
    const int strip = (f >> 3) & 3;
    const int pl = f >> 5;                 // [0, 128)
    const int pair = xcd * 128 + pl;       // [0, 1024)
    const int y = pair & 255;
    const int b = pair >> 8;

    const int t = threadIdx.x;
    const int l = t & 63;
    const int w = t >> 6;
    const int xs = strip << 7;
    const int jb = xs - 32;

    const int n   = l & 15;                // fragment row/col index
    const int n4  = n >> 2, nr = n & 3;
    const int ksl = (l >> 4) * 8;          // fragment k-start (within 32-half)
    const int qs  = ((l >> 4) & 3) << 2;   // lane-quarter swizzle bits

    __shared__ float lds[10240];           // 40 KB: x0 [0,4096), x1 [4096,10240)

    const float* x0r = x0 + (size_t)b * CF * CH + (size_t)y * WF;
    const float* x1r = x1 + (size_t)b * CF * CH + (size_t)y * WF;

    // ---- DMA source offsets (elements from x0r/x1r), lane-constant ----
    int o0[4], o1[6];
#pragma unroll
    for (int qi = 0; qi < 4; ++qi) {
        const int P = qi * 256 + t;                    // physical granule
        const int L = P ^ (((P >> 8) & 3) << 2);       // logical (involution)
        o0[qi] = (L >> 5) * (int)CH + xs + 4 * (L & 31);
    }
#pragma unroll
    for (int ri = 0; ri < 6; ++ri) {
        const int P = ri * 256 + t;                    // [0, 1536)
        const int c = P / 48;
        const int j4 = (P - 48 * c) ^ (((c >> 3) & 3) << 2);
        int jg = jb + 4 * j4;
        jg = jg < 0 ? 0 : (jg > 508 ? 508 : jg);       // clamp (zeroed at read)
        o1[ri] = c * (int)CH + jg;
    }

    // ---- swizzled ds_read bases (float indices), lane-constant ----
    const int A0b = (ksl * 32 + ((8 * w + n4) ^ qs)) * 4 + nr;
    const int A1b = (ksl * 32 + ((8 * w + 4 + n4) ^ qs)) * 4 + nr;
    int Bb[6];
#pragma unroll
    for (int jt = 0; jt < 6; ++jt)
        Bb[jt] = 4096 + (48 * ksl + ((8 * w + 4 * jt + n4) ^ qs)) * 4 + nr;

    f32x4 acc[10];
#pragma unroll
    for (int i = 0; i < 10; ++i) acc[i] = (f32x4)0.0f;

#define TRIPLE(ai, AH, AL) \
    do { \
        acc[ai] = __builtin_amdgcn_mfma_f32_16x16x32_f16(AH, bh, acc[ai], 0, 0, 0); \
        acc[ai] = __builtin_amdgcn_mfma_f32_16x16x32_f16(AH, bl, acc[ai], 0, 0, 0); \
        acc[ai] = __builtin_amdgcn_mfma_f32_16x16x32_f16(AL, bh, acc[ai], 0, 0, 0); \
    } while (0)

#pragma unroll
    for (int h = 0; h < 2; ++h) {
        const size_t hb = (size_t)h * 32 * CH;
        // ---- stage: 10 x 16B DMA per thread (wave-uniform LDS dest) ----
#pragma unroll
        for (int qi = 0; qi < 4; ++qi)
            __builtin_amdgcn_global_load_lds(
                (glb_void_t*)(x0r + hb + o0[qi]),
                (lds_void_t*)(lds + (qi * 256 + w * 64) * 4), 16, 0, 0);
#pragma unroll
        for (int ri = 0; ri < 6; ++ri)
            __builtin_amdgcn_global_load_lds(
                (glb_void_t*)(x1r + hb + o1[ri]),
                (lds_void_t*)(lds + 4096 + (ri * 256 + w * 64) * 4), 16, 0, 0);

        __syncthreads();                   // drains vmcnt + barrier

        // ---- A fragments (hi/lo) ----
        f16x8 ah0, al0, ah1, al1;
        {
            float ar[8];
#pragma unroll
            for (int i = 0; i < 8; ++i) ar[i] = lds[A0b + i * 128];
#pragma unroll
            for (int i = 0; i < 8; ++i) {
                const f16 hv = (f16)ar[i];
                ah0[i] = hv; al0[i] = (f16)(ar[i] - (float)hv);
            }
#pragma unroll
            for (int i = 0; i < 8; ++i) ar[i] = lds[A1b + i * 128];
#pragma unroll
            for (int i = 0; i < 8; ++i) {
                const f16 hv = (f16)ar[i];
                ah1[i] = hv; al1[i] = (f16)(ar[i] - (float)hv);
            }
        }

        // ---- B fragments + MFMA ----
#pragma unroll
        for (int jt = 0; jt < 6; ++jt) {
            float br[8];
#pragma unroll
            for (int i = 0; i < 8; ++i) br[i] = lds[Bb[jt] + i * 192];
            const bool okB = (unsigned)(jb + (2 * w + jt) * 16 + n) < (unsigned)WF;
            f16x8 bh, bl;
#pragma unroll
            for (int i = 0; i < 8; ++i) {
                const float v = okB ? br[i] : 0.f;
                const f16 hv = (f16)v;
                bh[i] = hv; bl[i] = (f16)(v - (float)hv);
            }
            if (jt < 5) TRIPLE(jt, ah0, al0);
            if (jt >= 1) TRIPLE(4 + jt, ah1, al1);
        }

        if (h == 0) __syncthreads();       // all reads done before restage
    }
#undef TRIPLE

    // ---- epilogue: band store (validated R5/R6).
    // C/D: col n = l&15, row m = (l>>4)*4+q ----
    f16* wsrow = ws + ((size_t)(b * HF + y) * WF) * DP;
#pragma unroll
    for (int xtl = 0; xtl < 2; ++xtl) {
#pragma unroll
        for (int p = 0; p < 5; ++p) {
            const int i = xtl * 5 + p;
#pragma unroll
            for (int q = 0; q < 4; ++q) {
                const int m = (l >> 4) * 4 + q;
                const int x = xs + (2 * w + xtl) * 16 + m;
                const int d = 16 * p + n - m;
                if ((unsigned)d < (unsigned)NDTOT)
                    wsrow[(size_t)x * DP + d] = (f16)acc[i][q];
            }
        }
    }
}

// ---------------------------------------------------------------------------
// k2: 3x3 box-sum over ws + scale: out[b,d,y,x] = INV * sum_{3x3} ws[y+dy][x+dx][d]
// grid (16 x-tiles of 32, 32 y-tiles of 8, b); 256 thr.
// ---------------------------------------------------------------------------
__global__ __launch_bounds__(256)
void corr_box(const f16* __restrict__ ws, float* __restrict__ out) {
    const int xt = blockIdx.x;
    const int yt = blockIdx.y;
    const int b = blockIdx.z;
    const int t = threadIdx.x;
    const int x0b = xt * 32, y0 = yt * 8;

    __shared__ f16 S[10 * 34][DP];     // 48.96 KB

    // stage (y0-1..y0+8) x (x0b-1..x0b+32) x 72d, OOB -> 0
    for (int u = 0; u < 10; ++u) {
        const int yy = y0 - 1 + u;
        const bool yok = (unsigned)yy < (unsigned)HF;
        const f16* src = ws + ((size_t)(b * HF + yy) * WF + (x0b - 1)) * DP;
#pragma unroll
        for (int sub = 0; sub < 2; ++sub) {
            const int idx = sub * 256 + t;
            if (idx < 306) {
                const int v = idx / 9, dg = idx - v * 9;
                const int xx = x0b - 1 + v;
                f16x8 val;
#pragma unroll
                for (int jj = 0; jj < 8; ++jj) val[jj] = (f16)0.f;
                if (yok && (unsigned)xx < (unsigned)WF)
                    val = *(const f16x8*)(src + (size_t)v * DP + dg * 8);
                *(f16x8*)&S[u * 34 + v][dg * 8] = val;
            }
        }
    }
    __syncthreads();

    const int ly = t >> 5, lx = t & 31;
    const int yg = y0 + ly, xg = x0b + lx;
    float* o0 = out + (size_t)b * NDTOT * WH + (size_t)yg * WF + xg;

#pragma unroll 1
    for (int dg = 0; dg < 9; ++dg) {
        f16x8 s;
#pragma unroll
        for (int jj = 0; jj < 8; ++jj) s[jj] = (f16)0.f;
#pragma unroll
        for (int du = 0; du < 3; ++du)
#pragma unroll
            for (int dv = 0; dv < 3; ++dv)
                s += *(const f16x8*)&S[(ly + du) * 34 + (lx + dv)][dg * 8];
#pragma unroll
        for (int jj = 0; jj < 8; ++jj) {
            const int d = dg * 8 + jj;
            if (d < NDTOT) o0[(size_t)d * WH] = (float)s[jj] * INV;
        }
    }
}

// ---------------------------------------------------------------------------
// Emergency fallback (tiny ws): direct computation, slow but correct.
// ---------------------------------------------------------------------------
__global__ void corr_naive(const float* __restrict__ x0, const float* __restrict__ x1,
                           float* __restrict__ out) {
    const size_t total = (size_t)4 * NDTOT * WH;
    size_t idx = (size_t)blockIdx.x * blockDim.x + threadIdx.x;
    if (idx >= total) return;
    const int j = (int)(idx % WF);
    const int i = (int)((idx / WF) % HF);
    const int d = (int)((idx / WH) % NDTOT);
    const int b = (int)(idx / ((size_t)NDTOT * WH));
    const int disp = d - 32;
    float s = 0.f;
    for (int u = i - 1; u <= i + 1; ++u) {
        if (u < 0 || u >= HF) continue;
        for (int v = j - 1; v <= j + 1; ++v) {
            if (v < 0 || v >= WF) continue;
            const int v1c = v + disp;
            if (v1c < 0 || v1c >= WF) continue;
            const float* p0 = x0 + (size_t)b * CF * CH + (size_t)u * WF + v;
            const float* p1 = x1 + (size_t)b * CF * CH + (size_t)u * WF + v1c;
            for (int c = 0; c < CF; ++c)
                s += p0[(size_t)c * CH] * p1[(size_t)c * CH];
        }
    }
    out[idx] = s * INV;
}

// ---------------------------------------------------------------------------
extern "C" void kernel_launch(void* const* d_in, const int* in_sizes, int n_in,
                              void* d_out, int out_size, void* d_ws, size_t ws_size,
                              hipStream_t stream) {
    const float* x0 = (const float*)d_in[0];
    const float* x1 = (const float*)d_in[1];
    float* out = (float*)d_out;

    const size_t wsNeed = (size_t)4 * HF * WF * DP * sizeof(f16);  // 75.5 MB

    if (ws_size >= wsNeed) {
        f16* ws = (f16*)d_ws;
        corr_gram<<<dim3(4096), dim3(256), 0, stream>>>(x0, x1, ws);
        corr_box<<<dim3(16, 32, 4), dim3(256), 0, stream>>>(ws, out);
    } else {
        const size_t total = (size_t)4 * NDTOT * WH;
        const int blocks = (int)((total + 255) / 256);
        corr_naive<<<dim3(blocks), dim3(256), 0, stream>>>(x0, x1, out);
    }
}

// Round 9
// 128.325 us; speedup vs baseline: 2.2310x; 1.0666x over previous
//
#include <hip/hip_runtime.h>

#define WF 512
#define HF 256
#define CF 64
#define NDTOT 65
#define DP 72            // padded d-stride in ws (f16 elements), 144 B rows

static constexpr size_t CH  = (size_t)HF * WF;
static constexpr size_t WH  = (size_t)HF * WF;
static constexpr float  INV = 1.0f / 576.0f;

typedef _Float16 f16;
typedef _Float16 f16x8 __attribute__((ext_vector_type(8)));
typedef float    f32x4 __attribute__((ext_vector_type(4)));

typedef __attribute__((address_space(3))) void lds_void_t;
typedef const __attribute__((address_space(1))) void glb_void_t;

// ---------------------------------------------------------------------------
// k1: banded Gram via MFMA, fp16 hi/lo split (hh + hl + lh).
// Per (b, y, strip of 128 x-cols): G[x,j] = sum_c x0[c,x]*x1[c,j],
// j-x in [-32,32]; stored ws[b][y][x][d=j-x+32] (f16).
// Data path (validated R7): per 32-ch K-half, x0(128) + x1(192 cols) staged
// raw f32 into 40 KB LDS via global_load_lds 16B DMAs, granule-XOR swizzled;
// fragments read from LDS, cvt to f16 hi/lo, 60 MFMAs/wave.
// R8 epilogue (R9: store-count FIXED): band scattered to a [128][72] f16
// LDS tile (exactly-once coverage: d=16p+n-m <-> unique (p,n)), pad zeroed,
// then 1152 coalesced 16B chunks stored cooperatively (ws block-row is
// contiguous). [R8 bug: stored 2304 chunks = 18KB overrun into the next
// block's ws region -> cross-block race -> NaN.]
// ---------------------------------------------------------------------------
__global__ __launch_bounds__(256, 4)
void corr_gram(const float* __restrict__ x0, const float* __restrict__ x1,
               f16* __restrict__ ws) {
    // XCD swizzle: all 4 strips of one (b,y) on one XCD, dispatched adjacently.
    const int f = blockIdx.x;              // [0, 4096)
    const int xcd = f & 7;
    const int strip = (f >> 3) & 3;
    const int pl = f >> 5;                 // [0, 128)
    const int pair = xcd * 128 + pl;       // [0, 1024)
    const int y = pair & 255;
    const int b = pair >> 8;

    const int t = threadIdx.x;
    const int l = t & 63;
    const int w = t >> 6;
    const int xs = strip << 7;
    const int jb = xs - 32;

    const int n   = l & 15;                // fragment row/col index
    const int n4  = n >> 2, nr = n & 3;
    const int ksl = (l >> 4) * 8;          // fragment k-start (within 32-half)
    const int qs  = ((l >> 4) & 3) << 2;   // lane-quarter swizzle bits

    __shared__ float lds[10240];           // 40 KB: x0 [0,4096), x1 [4096,10240)

    const float* x0r = x0 + (size_t)b * CF * CH + (size_t)y * WF;
    const float* x1r = x1 + (size_t)b * CF * CH + (size_t)y * WF;

    // ---- DMA source offsets (elements from x0r/x1r), lane-constant ----
    int o0[4], o1[6];
#pragma unroll
    for (int qi = 0; qi < 4; ++qi) {
        const int P = qi * 256 + t;                    // physical granule
        const int L = P ^ (((P >> 8) & 3) << 2);       // logical (involution)
        o0[qi] = (L >> 5) * (int)CH + xs + 4 * (L & 31);
    }
#pragma unroll
    for (int ri = 0; ri < 6; ++ri) {
        const int P = ri * 256 + t;                    // [0, 1536)
        const int c = P / 48;
        const int j4 = (P - 48 * c) ^ (((c >> 3) & 3) << 2);
        int jg = jb + 4 * j4;
        jg = jg < 0 ? 0 : (jg > 508 ? 508 : jg);       // clamp (zeroed at read)
        o1[ri] = c * (int)CH + jg;
    }

    // ---- swizzled ds_read bases (float indices), lane-constant ----
    const int A0b = (ksl * 32 + ((8 * w + n4) ^ qs)) * 4 + nr;
    const int A1b = (ksl * 32 + ((8 * w + 4 + n4) ^ qs)) * 4 + nr;
    int Bb[6];
#pragma unroll
    for (int jt = 0; jt < 6; ++jt)
        Bb[jt] = 4096 + (48 * ksl + ((8 * w + 4 * jt + n4) ^ qs)) * 4 + nr;

    f32x4 acc[10];
#pragma unroll
    for (int i = 0; i < 10; ++i) acc[i] = (f32x4)0.0f;

#define TRIPLE(ai, AH, AL) \
    do { \
        acc[ai] = __builtin_amdgcn_mfma_f32_16x16x32_f16(AH, bh, acc[ai], 0, 0, 0); \
        acc[ai] = __builtin_amdgcn_mfma_f32_16x16x32_f16(AH, bl, acc[ai], 0, 0, 0); \
        acc[ai] = __builtin_amdgcn_mfma_f32_16x16x32_f16(AL, bh, acc[ai], 0, 0, 0); \
    } while (0)

#pragma unroll
    for (int h = 0; h < 2; ++h) {
        const size_t hb = (size_t)h * 32 * CH;
        // ---- stage: 10 x 16B DMA per thread (wave-uniform LDS dest) ----
#pragma unroll
        for (int qi = 0; qi < 4; ++qi)
            __builtin_amdgcn_global_load_lds(
                (glb_void_t*)(x0r + hb + o0[qi]),
                (lds_void_t*)(lds + (qi * 256 + w * 64) * 4), 16, 0, 0);
#pragma unroll
        for (int ri = 0; ri < 6; ++ri)
            __builtin_amdgcn_global_load_lds(
                (glb_void_t*)(x1r + hb + o1[ri]),
                (lds_void_t*)(lds + 4096 + (ri * 256 + w * 64) * 4), 16, 0, 0);

        __syncthreads();                   // drains vmcnt + barrier

        // ---- A fragments (hi/lo) ----
        f16x8 ah0, al0, ah1, al1;
        {
            float ar[8];
#pragma unroll
            for (int i = 0; i < 8; ++i) ar[i] = lds[A0b + i * 128];
#pragma unroll
            for (int i = 0; i < 8; ++i) {
                const f16 hv = (f16)ar[i];
                ah0[i] = hv; al0[i] = (f16)(ar[i] - (float)hv);
            }
#pragma unroll
            for (int i = 0; i < 8; ++i) ar[i] = lds[A1b + i * 128];
#pragma unroll
            for (int i = 0; i < 8; ++i) {
                const f16 hv = (f16)ar[i];
                ah1[i] = hv; al1[i] = (f16)(ar[i] - (float)hv);
            }
        }

        // ---- B fragments + MFMA ----
#pragma unroll
        for (int jt = 0; jt < 6; ++jt) {
            float br[8];
#pragma unroll
            for (int i = 0; i < 8; ++i) br[i] = lds[Bb[jt] + i * 192];
            const bool okB = (unsigned)(jb + (2 * w + jt) * 16 + n) < (unsigned)WF;
            f16x8 bh, bl;
#pragma unroll
            for (int i = 0; i < 8; ++i) {
                const float v = okB ? br[i] : 0.f;
                const f16 hv = (f16)v;
                bh[i] = hv; bl[i] = (f16)(v - (float)hv);
            }
            if (jt < 5) TRIPLE(jt, ah0, al0);
            if (jt >= 1) TRIPLE(4 + jt, ah1, al1);
        }

        __syncthreads();                   // reads done before LDS reuse
    }
#undef TRIPLE

    // ---- epilogue: LDS transpose -> coalesced wide stores ----
    // eb: [128 x-local][72 d] f16 tile (18432 B, reuses staging LDS).
    f16* eb = (f16*)lds;

    // scatter band values (C/D layout validated R5-R7: col n=l&15, row m=(l>>4)*4+q)
#pragma unroll
    for (int xtl = 0; xtl < 2; ++xtl) {
#pragma unroll
        for (int p = 0; p < 5; ++p) {
            const int i = xtl * 5 + p;
#pragma unroll
            for (int q = 0; q < 4; ++q) {
                const int m = (l >> 4) * 4 + q;
                const int xl = (2 * w + xtl) * 16 + m;
                const int d = 16 * p + n - m;
                if ((unsigned)d < (unsigned)NDTOT)
                    eb[xl * DP + d] = (f16)acc[i][q];
            }
        }
    }
    // zero pad columns d=65..71 (128 x 7 = 896 entries)
#pragma unroll
    for (int i = 0; i < 4; ++i) {
        const int idx = t + 256 * i;
        if (idx < 896) {
            const int xl = idx / 7;
            eb[xl * DP + NDTOT + (idx - 7 * xl)] = (f16)0.f;
        }
    }
    __syncthreads();

    // cooperative coalesced store: 128*72 f16 = 18432 B = 1152 x 16B chunks
    uint4* dst = (uint4*)(ws + ((size_t)(b * HF + y) * WF + xs) * DP);
    const uint4* src = (const uint4*)eb;
#pragma unroll
    for (int i = 0; i < 5; ++i) {
        const int idx = t + 256 * i;
        if (idx < 1152) dst[idx] = src[idx];
    }
}

// ---------------------------------------------------------------------------
// k2: 3x3 box-sum over ws + scale: out[b,d,y,x] = INV * sum_{3x3} ws[y+dy][x+dx][d]
// grid (16 x-tiles of 32, 32 y-tiles of 8, b); 256 thr.
// ---------------------------------------------------------------------------
__global__ __launch_bounds__(256)
void corr_box(const f16* __restrict__ ws, float* __restrict__ out) {
    const int xt = blockIdx.x;
    const int yt = blockIdx.y;
    const int b = blockIdx.z;
    const int t = threadIdx.x;
    const int x0b = xt * 32, y0 = yt * 8;

    __shared__ f16 S[10 * 34][DP];     // 48.96 KB

    // stage (y0-1..y0+8) x (x0b-1..x0b+32) x 72d, OOB -> 0
    for (int u = 0; u < 10; ++u) {
        const int yy = y0 - 1 + u;
        const bool yok = (unsigned)yy < (unsigned)HF;
        const f16* src = ws + ((size_t)(b * HF + yy) * WF + (x0b - 1)) * DP;
#pragma unroll
        for (int sub = 0; sub < 2; ++sub) {
            const int idx = sub * 256 + t;
            if (idx < 306) {
                const int v = idx / 9, dg = idx - v * 9;
                const int xx = x0b - 1 + v;
                f16x8 val;
#pragma unroll
                for (int jj = 0; jj < 8; ++jj) val[jj] = (f16)0.f;
                if (yok && (unsigned)xx < (unsigned)WF)
                    val = *(const f16x8*)(src + (size_t)v * DP + dg * 8);
                *(f16x8*)&S[u * 34 + v][dg * 8] = val;
            }
        }
    }
    __syncthreads();

    const int ly = t >> 5, lx = t & 31;
    const int yg = y0 + ly, xg = x0b + lx;
    float* o0 = out + (size_t)b * NDTOT * WH + (size_t)yg * WF + xg;

#pragma unroll 1
    for (int dg = 0; dg < 9; ++dg) {
        f16x8 s;
#pragma unroll
        for (int jj = 0; jj < 8; ++jj) s[jj] = (f16)0.f;
#pragma unroll
        for (int du = 0; du < 3; ++du)
#pragma unroll
            for (int dv = 0; dv < 3; ++dv)
                s += *(const f16x8*)&S[(ly + du) * 34 + (lx + dv)][dg * 8];
#pragma unroll
        for (int jj = 0; jj < 8; ++jj) {
            const int d = dg * 8 + jj;
            if (d < NDTOT) o0[(size_t)d * WH] = (float)s[jj] * INV;
        }
    }
}

// ---------------------------------------------------------------------------
// Emergency fallback (tiny ws): direct computation, slow but correct.
// ---------------------------------------------------------------------------
__global__ void corr_naive(const float* __restrict__ x0, const float* __restrict__ x1,
                           float* __restrict__ out) {
    const size_t total = (size_t)4 * NDTOT * WH;
    size_t idx = (size_t)blockIdx.x * blockDim.x + threadIdx.x;
    if (idx >= total) return;
    const int j = (int)(idx % WF);
    const int i = (int)((idx / WF) % HF);
    const int d = (int)((idx / WH) % NDTOT);
    const int b = (int)(idx / ((size_t)NDTOT * WH));
    const int disp = d - 32;
    float s = 0.f;
    for (int u = i - 1; u <= i + 1; ++u) {
        if (u < 0 || u >= HF) continue;
        for (int v = j - 1; v <= j + 1; ++v) {
            if (v < 0 || v >= WF) continue;
            const int v1c = v + disp;
            if (v1c < 0 || v1c >= WF) continue;
            const float* p0 = x0 + (size_t)b * CF * CH + (size_t)u * WF + v;
            const float* p1 = x1 + (size_t)b * CF * CH + (size_t)u * WF + v1c;
            for (int c = 0; c < CF; ++c)
                s += p0[(size_t)c * CH] * p1[(size_t)c * CH];
        }
    }
    out[idx] = s * INV;
}

// ---------------------------------------------------------------------------
extern "C" void kernel_launch(void* const* d_in, const int* in_sizes, int n_in,
                              void* d_out, int out_size, void* d_ws, size_t ws_size,
                              hipStream_t stream) {
    const float* x0 = (const float*)d_in[0];
    const float* x1 = (const float*)d_in[1];
    float* out = (float*)d_out;

    const size_t wsNeed = (size_t)4 * HF * WF * DP * sizeof(f16);  // 75.5 MB

    if (ws_size >= wsNeed) {
        f16* ws = (f16*)d_ws;
        corr_gram<<<dim3(4096), dim3(256), 0, stream>>>(x0, x1, ws);
        corr_box<<<dim3(16, 32, 4), dim3(256), 0, stream>>>(ws, out);
    } else {
        const size_t total = (size_t)4 * NDTOT * WH;
        const int blocks = (int)((total + 255) / 256);
        corr_naive<<<dim3(blocks), dim3(256), 0, stream>>>(x0, x1, out);
    }
}

// Round 10
// 128.145 us; speedup vs baseline: 2.2341x; 1.0014x over previous
//
#include <hip/hip_runtime.h>

#define WF 512
#define HF 256
#define CF 64
#define NDTOT 65
#define DP 72            // padded d-stride in ws (f16 elements), 144 B rows

static constexpr size_t CH  = (size_t)HF * WF;
static constexpr size_t WH  = (size_t)HF * WF;
static constexpr float  INV = 1.0f / 576.0f;

typedef _Float16 f16;
typedef _Float16 f16x8 __attribute__((ext_vector_type(8)));
typedef float    f32x4 __attribute__((ext_vector_type(4)));

typedef __attribute__((address_space(3))) void lds_void_t;
typedef const __attribute__((address_space(1))) void glb_void_t;

#define WAIT_VM10() asm volatile("s_waitcnt vmcnt(10)" ::: "memory")
#define WAIT_VM0()  asm volatile("s_waitcnt vmcnt(0)" ::: "memory")
#define WAIT_LGKM() asm volatile("s_waitcnt lgkmcnt(0)" ::: "memory")
#define BAR()       __builtin_amdgcn_s_barrier()
#define SFENCE()    __builtin_amdgcn_sched_barrier(0)

// ---------------------------------------------------------------------------
// k1: banded Gram via MFMA, fp16 hi/lo split (hh+hl+lh). PIPELINED (R10).
// One persistent block per (b,y); 8 stages = 4 strips x 2 K-halves.
// Double-buffered 40 KB LDS halves (80 KB total); DMA for stage s+2 issued
// after stage s's reads; counted s_waitcnt vmcnt(10) at stage top keeps the
// next stage's 10 loads in flight across all barriers (never drain to 0
// mid-loop). Raw s_barrier + manual lgkmcnt(0) before publishing barriers.
// Per-stage data path / swizzles / MFMA tiling / epilogue = R9 (PASSed).
// ---------------------------------------------------------------------------
__global__ __launch_bounds__(256, 2)
void corr_gram(const float* __restrict__ x0, const float* __restrict__ x1,
               f16* __restrict__ ws) {
    const int blk = blockIdx.x;            // [0,1024) = (b,y)
    const int y = blk & 255;
    const int b = blk >> 8;

    const int t = threadIdx.x;
    const int l = t & 63;
    const int w = t >> 6;

    const int n   = l & 15;                // fragment row/col index
    const int n4  = n >> 2, nr = n & 3;
    const int ksl = (l >> 4) * 8;          // fragment k-start (within 32-half)
    const int qs  = ((l >> 4) & 3) << 2;   // lane-quarter swizzle bits

    __shared__ float lds_flat[20480];      // 80 KB = 2 x 40 KB stage buffers

    const float* x0r = x0 + (size_t)b * CF * CH + (size_t)y * WF;
    const float* x1r = x1 + (size_t)b * CF * CH + (size_t)y * WF;

    // ---- strip-independent DMA source pieces (validated R9) ----
    int o0c[4];                            // x0: + xs per tile
#pragma unroll
    for (int qi = 0; qi < 4; ++qi) {
        const int P = qi * 256 + t;
        const int L = P ^ (((P >> 8) & 3) << 2);
        o0c[qi] = (L >> 5) * (int)CH + 4 * (L & 31);
    }
    int oc1[6], jo[6];                     // x1: c*CH + clamp(jb + jo)
#pragma unroll
    for (int ri = 0; ri < 6; ++ri) {
        const int P = ri * 256 + t;
        const int c = P / 48;
        const int j4 = (P - 48 * c) ^ (((c >> 3) & 3) << 2);
        oc1[ri] = c * (int)CH;
        jo[ri] = 4 * j4;
    }

    // ---- swizzled ds_read bases (floats, buffer-relative; strip-indep) ----
    const int A0b = (ksl * 32 + ((8 * w + n4) ^ qs)) * 4 + nr;
    const int A1b = (ksl * 32 + ((8 * w + 4 + n4) ^ qs)) * 4 + nr;
    int Bb[6];
#pragma unroll
    for (int jt = 0; jt < 6; ++jt)
        Bb[jt] = 4096 + (48 * ksl + ((8 * w + 4 * jt + n4) ^ qs)) * 4 + nr;

    // ---- stage issue: 10 x 16B DMA, wave-uniform LDS dest ----
    auto issue_stage = [&](int s2) {
        const int st2 = s2 >> 1, hf2 = s2 & 1;
        const int xs2 = st2 << 7, jb2 = xs2 - 32;
        float* dstb = lds_flat + (s2 & 1) * 10240;
        const float* g0 = x0r + (size_t)(hf2 * 32) * CH;
        const float* g1 = x1r + (size_t)(hf2 * 32) * CH;
#pragma unroll
        for (int qi = 0; qi < 4; ++qi)
            __builtin_amdgcn_global_load_lds(
                (glb_void_t*)(g0 + o0c[qi] + xs2),
                (lds_void_t*)(dstb + (qi * 256 + w * 64) * 4), 16, 0, 0);
#pragma unroll
        for (int ri = 0; ri < 6; ++ri) {
            int jg = jb2 + jo[ri];
            jg = jg < 0 ? 0 : (jg > 508 ? 508 : jg);   // clamp (zeroed at read)
            __builtin_amdgcn_global_load_lds(
                (glb_void_t*)(g1 + oc1[ri] + jg),
                (lds_void_t*)(dstb + 4096 + (ri * 256 + w * 64) * 4), 16, 0, 0);
        }
    };

#define TRIPLE(ai, AH, AL) \
    do { \
        acc[ai] = __builtin_amdgcn_mfma_f32_16x16x32_f16(AH, bh, acc[ai], 0, 0, 0); \
        acc[ai] = __builtin_amdgcn_mfma_f32_16x16x32_f16(AH, bl, acc[ai], 0, 0, 0); \
        acc[ai] = __builtin_amdgcn_mfma_f32_16x16x32_f16(AL, bh, acc[ai], 0, 0, 0); \
    } while (0)

    f32x4 acc[10];

    issue_stage(0);
    issue_stage(1);

#pragma unroll 1
    for (int s = 0; s < 8; ++s) {
        const int st = s >> 1;
        const int xs = st << 7, jb = xs - 32;
        const float* bufc = lds_flat + (s & 1) * 10240;

        if (s & 1) {
            // odd stage: continue accumulating this strip's acc
        } else {
#pragma unroll
            for (int i = 0; i < 10; ++i) acc[i] = (f32x4)0.0f;
        }

        if (s < 7) WAIT_VM10(); else WAIT_VM0();
        SFENCE();
        BAR();                              // stage-s data visible to all waves
        SFENCE();

        // ---- A fragments (hi/lo) ----
        f16x8 ah0, al0, ah1, al1;
        {
            float ar[8];
#pragma unroll
            for (int i = 0; i < 8; ++i) ar[i] = bufc[A0b + i * 128];
#pragma unroll
            for (int i = 0; i < 8; ++i) {
                const f16 hv = (f16)ar[i];
                ah0[i] = hv; al0[i] = (f16)(ar[i] - (float)hv);
            }
#pragma unroll
            for (int i = 0; i < 8; ++i) ar[i] = bufc[A1b + i * 128];
#pragma unroll
            for (int i = 0; i < 8; ++i) {
                const f16 hv = (f16)ar[i];
                ah1[i] = hv; al1[i] = (f16)(ar[i] - (float)hv);
            }
        }

        // ---- B fragments + MFMA ----
#pragma unroll
        for (int jt = 0; jt < 6; ++jt) {
            float br[8];
#pragma unroll
            for (int i = 0; i < 8; ++i) br[i] = bufc[Bb[jt] + i * 192];
            const bool okB = (unsigned)(jb + (2 * w + jt) * 16 + n) < (unsigned)WF;
            f16x8 bh, bl;
#pragma unroll
            for (int i = 0; i < 8; ++i) {
                const float v = okB ? br[i] : 0.f;
                const f16 hv = (f16)v;
                bh[i] = hv; bl[i] = (f16)(v - (float)hv);
            }
            if (jt < 5) TRIPLE(jt, ah0, al0);
            if (jt >= 1) TRIPLE(4 + jt, ah1, al1);
        }

        if (s & 1) {
            // ---- tile end: epilogue through LDS (reuses buf[s&1]) ----
            WAIT_LGKM();
            BAR();                          // all waves done reading buf[s&1]
            SFENCE();
            f16* eb = (f16*)bufc;
            // scatter band (C/D layout validated R5-R9)
#pragma unroll
            for (int xtl = 0; xtl < 2; ++xtl) {
#pragma unroll
                for (int p = 0; p < 5; ++p) {
                    const int i = xtl * 5 + p;
#pragma unroll
                    for (int q = 0; q < 4; ++q) {
                        const int m = (l >> 4) * 4 + q;
                        const int xl = (2 * w + xtl) * 16 + m;
                        const int d = 16 * p + n - m;
                        if ((unsigned)d < (unsigned)NDTOT)
                            eb[xl * DP + d] = (f16)acc[i][q];
                    }
                }
            }
            // zero pad columns d=65..71 (128 x 7 entries)
#pragma unroll
            for (int i = 0; i < 4; ++i) {
                const int idx = t + 256 * i;
                if (idx < 896) {
                    const int xl = idx / 7;
                    eb[xl * DP + NDTOT + (idx - 7 * xl)] = (f16)0.f;
                }
            }
            WAIT_LGKM();                    // my ds_writes done before barrier
            BAR();
            SFENCE();
            // coalesced store: 128*72 f16 = 1152 x 16B chunks
            uint4* dst = (uint4*)(ws + ((size_t)(b * HF + y) * WF + xs) * DP);
            const uint4* src = (const uint4*)eb;
#pragma unroll
            for (int i = 0; i < 5; ++i) {
                const int idx = t + 256 * i;
                if (idx < 1152) dst[idx] = src[idx];
            }
            WAIT_LGKM();                    // LDS reads for stores complete
            BAR();                          // before re-DMA into this buffer
            SFENCE();
            if (s + 2 < 8) issue_stage(s + 2);
        } else {
            WAIT_LGKM();
            BAR();                          // all waves done reading buf[s&1]
            SFENCE();
            if (s + 2 < 8) issue_stage(s + 2);
        }
    }
#undef TRIPLE
}

// ---------------------------------------------------------------------------
// k2: 3x3 box-sum over ws + scale: out[b,d,y,x] = INV * sum_{3x3} ws[y+dy][x+dx][d]
// grid (16 x-tiles of 32, 32 y-tiles of 8, b); 256 thr.
// ---------------------------------------------------------------------------
__global__ __launch_bounds__(256)
void corr_box(const f16* __restrict__ ws, float* __restrict__ out) {
    const int xt = blockIdx.x;
    const int yt = blockIdx.y;
    const int b = blockIdx.z;
    const int t = threadIdx.x;
    const int x0b = xt * 32, y0 = yt * 8;

    __shared__ f16 S[10 * 34][DP];     // 48.96 KB

    // stage (y0-1..y0+8) x (x0b-1..x0b+32) x 72d, OOB -> 0
    for (int u = 0; u < 10; ++u) {
        const int yy = y0 - 1 + u;
        const bool yok = (unsigned)yy < (unsigned)HF;
        const f16* src = ws + ((size_t)(b * HF + yy) * WF + (x0b - 1)) * DP;
#pragma unroll
        for (int sub = 0; sub < 2; ++sub) {
            const int idx = sub * 256 + t;
            if (idx < 306) {
                const int v = idx / 9, dg = idx - v * 9;
                const int xx = x0b - 1 + v;
                f16x8 val;
#pragma unroll
                for (int jj = 0; jj < 8; ++jj) val[jj] = (f16)0.f;
                if (yok && (unsigned)xx < (unsigned)WF)
                    val = *(const f16x8*)(src + (size_t)v * DP + dg * 8);
                *(f16x8*)&S[u * 34 + v][dg * 8] = val;
            }
        }
    }
    __syncthreads();

    const int ly = t >> 5, lx = t & 31;
    const int yg = y0 + ly, xg = x0b + lx;
    float* o0 = out + (size_t)b * NDTOT * WH + (size_t)yg * WF + xg;

#pragma unroll 1
    for (int dg = 0; dg < 9; ++dg) {
        f16x8 s;
#pragma unroll
        for (int jj = 0; jj < 8; ++jj) s[jj] = (f16)0.f;
#pragma unroll
        for (int du = 0; du < 3; ++du)
#pragma unroll
            for (int dv = 0; dv < 3; ++dv)
                s += *(const f16x8*)&S[(ly + du) * 34 + (lx + dv)][dg * 8];
#pragma unroll
        for (int jj = 0; jj < 8; ++jj) {
            const int d = dg * 8 + jj;
            if (d < NDTOT) o0[(size_t)d * WH] = (float)s[jj] * INV;
        }
    }
}

// ---------------------------------------------------------------------------
// Emergency fallback (tiny ws): direct computation, slow but correct.
// ---------------------------------------------------------------------------
__global__ void corr_naive(const float* __restrict__ x0, const float* __restrict__ x1,
                           float* __restrict__ out) {
    const size_t total = (size_t)4 * NDTOT * WH;
    size_t idx = (size_t)blockIdx.x * blockDim.x + threadIdx.x;
    if (idx >= total) return;
    const int j = (int)(idx % WF);
    const int i = (int)((idx / WF) % HF);
    const int d = (int)((idx / WH) % NDTOT);
    const int b = (int)(idx / ((size_t)NDTOT * WH));
    const int disp = d - 32;
    float s = 0.f;
    for (int u = i - 1; u <= i + 1; ++u) {
        if (u < 0 || u >= HF) continue;
        for (int v = j - 1; v <= j + 1; ++v) {
            if (v < 0 || v >= WF) continue;
            const int v1c = v + disp;
            if (v1c < 0 || v1c >= WF) continue;
            const float* p0 = x0 + (size_t)b * CF * CH + (size_t)u * WF + v;
            const float* p1 = x1 + (size_t)b * CF * CH + (size_t)u * WF + v1c;
            for (int c = 0; c < CF; ++c)
                s += p0[(size_t)c * CH] * p1[(size_t)c * CH];
        }
    }
    out[idx] = s * INV;
}

// ---------------------------------------------------------------------------
extern "C" void kernel_launch(void* const* d_in, const int* in_sizes, int n_in,
                              void* d_out, int out_size, void* d_ws, size_t ws_size,
                              hipStream_t stream) {
    const float* x0 = (const float*)d_in[0];
    const float* x1 = (const float*)d_in[1];
    float* out = (float*)d_out;

    const size_t wsNeed = (size_t)4 * HF * WF * DP * sizeof(f16);  // 75.5 MB

    if (ws_size >= wsNeed) {
        f16* ws = (f16*)d_ws;
        corr_gram<<<dim3(1024), dim3(256), 0, stream>>>(x0, x1, ws);
        corr_box<<<dim3(16, 32, 4), dim3(256), 0, stream>>>(ws, out);
    } else {
        const size_t total = (size_t)4 * NDTOT * WH;
        const int blocks = (int)((total + 255) / 256);
        corr_naive<<<dim3(blocks), dim3(256), 0, stream>>>(x0, x1, out);
    }
}